// Round 2
// baseline (177.289 us; speedup 1.0000x reference)
//
#include <hip/hip_runtime.h>
#include <hip/hip_cooperative_groups.h>
#include <math.h>

namespace cg = cooperative_groups;

#define BETA 0.001f
#define WPB  4          // waves per block; one segment per wave

// softplus(x_j - x_i) (i<j) = 0.5*h(x_j-x_i) + 0.5*(x_j-x_i),
//   h(d) = |d| + 2*ln(1+e^{-|d|})
// Sum over pairs:
//   sum_{i<j} softplus = 0.25*(S_full - L*h(0)) + 0.5*sum_k x_k*(2k-L+1)
//   where S_full sums h over ALL ordered (i,j) incl. diagonal, h(0)=2 ln 2.
// l2 term separable: sum_pairs 0.5*(pos^2+neg^2) = 0.5*(L-1)*sum(x^2).
//
// Transcendental reduction: per chain accumulate
//   su = sum |d|,  p = prod (1 + e^{-|d|})   (factors in (1,2], <=127 of
//   them -> p <= 2^127 < FLT_MAX, no overflow)
// then  sum h = su + 2*ln2 * log2(p)  -> ONE v_log_f32 per chain total.
//
// v3 structural change vs v2 (70.5 us):
//  * ONE dispatch instead of two. Counters showed both my kernels are
//    tiny (<40 us fills dominate the trace); the ~30 us controllable
//    budget is mostly per-dispatch launch overhead/gaps. Fuse the final
//    reduce via cooperative launch + grid sync: each block stores one
//    partial to d_ws, grid.sync(), block 0 sums 1024 floats -> out.
//    Grid is 1024 blocks x 4 waves = 4096 waves <= 8192 capacity, so
//    co-residency for hipLaunchCooperativeKernel is guaranteed.

__device__ __forceinline__ float lane_bcast(float v, int lane_u) {
    // wave-uniform lane index -> v_readlane_b32 (no LDS, no lgkmcnt)
    return __uint_as_float(
        (unsigned)__builtin_amdgcn_readlane((int)__float_as_uint(v), lane_u));
}

__global__ __launch_bounds__(WPB * 64) void rmloss_coop(
    const float* __restrict__ logits,
    const int*   __restrict__ cu,
    float*       __restrict__ part,   // [gridDim.x] block partials (d_ws)
    float*       __restrict__ out,
    int n_seg, float inv_n)
{
    const int wave = threadIdx.x >> 6;
    const int lane = threadIdx.x & 63;
    const int s = blockIdx.x * WPB + wave;

    __shared__ float wsum[WPB];

    const float kNL2E = -1.44269504088896340736f;  // -log2(e)
    const float kT2L2 =  1.38629436111989061883f;  //  2*ln(2)

    float segval = 0.0f;                // lane0-of-wave contribution

    if (s < n_seg) {                    // wave-uniform guard, NO early return
        const int a   = cu[s];
        const int L   = cu[s + 1] - a;  // 32..127
        const int Lm1 = L - 1;

        const bool a_ok = lane < L;
        const bool b_ok = lane + 64 < L;
        const float va = a_ok ? logits[a + lane] : 0.0f;
        const float vb = b_ok ? logits[a + lane + 64] : 0.0f;

        float su_a = 0.0f, p_a = 1.0f;
        float su_b = 0.0f, p_b = 1.0f;

        if (L > 64) {                       // all va lanes valid here
            #pragma unroll 4
            for (int j = 0; j < 64; ++j) {  // broadcast x[0..63] from va regs
                const float v  = lane_bcast(va, j);
                const float ua = fabsf(va - v);
                su_a += ua;
                p_a = fmaf(p_a, __builtin_amdgcn_exp2f(ua * kNL2E), p_a);
                const float ub = fabsf(vb - v);
                su_b += ub;
                p_b = fmaf(p_b, __builtin_amdgcn_exp2f(ub * kNL2E), p_b);
            }
            const int t2 = L - 64;          // 1..63
            #pragma unroll 4
            for (int j = 0; j < t2; ++j) {  // broadcast x[64..L-1] from vb regs
                const float v  = lane_bcast(vb, j);
                const float ua = fabsf(va - v);
                su_a += ua;
                p_a = fmaf(p_a, __builtin_amdgcn_exp2f(ua * kNL2E), p_a);
                const float ub = fabsf(vb - v);
                su_b += ub;
                p_b = fmaf(p_b, __builtin_amdgcn_exp2f(ub * kNL2E), p_b);
            }
        } else {
            #pragma unroll 4
            for (int j = 0; j < L; ++j) {
                const float v  = lane_bcast(va, j);
                const float ua = fabsf(va - v);
                su_a += ua;
                p_a = fmaf(p_a, __builtin_amdgcn_exp2f(ua * kNL2E), p_a);
            }
        }

        // one log2 per chain (v_log_f32 IS log2 on gfx950)
        const float ha = su_a + kT2L2 * __builtin_amdgcn_logf(p_a);
        const float hb = su_b + kT2L2 * __builtin_amdgcn_logf(p_b);
        const float acch = (a_ok ? ha : 0.0f) + (b_ok ? hb : 0.0f);

        const float lin = va * (float)(2 * lane - Lm1)
                        + vb * (float)(2 * (lane + 64) - Lm1);
        const float sq  = va * va + vb * vb;

        float f = 0.25f * acch + 0.5f * lin + (0.5f * BETA * (float)Lm1) * sq;
        #pragma unroll
        for (int off = 32; off > 0; off >>= 1)
            f += __shfl_down(f, off, 64);

        if (lane == 0) {
            const float P    = 0.5f * (float)(L * Lm1);
            const float diag = 0.25f * (float)L * kT2L2;  // 0.25*L*h(0)
            segval = (f - diag) / P * inv_n;
        }
    }

    if (lane == 0) wsum[wave] = segval;     // inactive waves contribute 0
    __syncthreads();
    if (threadIdx.x == 0)
        part[blockIdx.x] = (wsum[0] + wsum[1]) + (wsum[2] + wsum[3]);

    __threadfence();                        // release partials (cross-XCD)
    cg::this_grid().sync();

    if (blockIdx.x == 0) {
        __threadfence();                    // acquire side (invalidate stale)
        const int t    = threadIdx.x;
        const int nblk = (int)gridDim.x;
        float acc = 0.0f;

        const int n4 = nblk >> 2;
        const float4* __restrict__ p4 = (const float4*)part;
        for (int i = t; i < n4; i += WPB * 64) {
            const float4 v = p4[i];
            acc += (v.x + v.y) + (v.z + v.w);
        }
        for (int i = (n4 << 2) + t; i < nblk; i += WPB * 64)  // tail
            acc += part[i];

        #pragma unroll
        for (int off = 32; off > 0; off >>= 1)
            acc += __shfl_down(acc, off, 64);

        if (lane == 0) wsum[wave] = acc;    // reuse LDS (block-local)
        __syncthreads();
        if (t == 0)
            out[0] = (wsum[0] + wsum[1]) + (wsum[2] + wsum[3]);
    }
}

extern "C" void kernel_launch(void* const* d_in, const int* in_sizes, int n_in,
                              void* d_out, int out_size, void* d_ws, size_t ws_size,
                              hipStream_t stream) {
    (void)n_in; (void)out_size; (void)ws_size;

    const float* logits = (const float*)d_in[0];
    const int*   cu     = (const int*)d_in[1];
    float*       out    = (float*)d_out;
    float*       part   = (float*)d_ws;          // 4*nblocks = 4 KB of ws

    int n_seg  = in_sizes[1] - 1;
    int blocks = (n_seg + WPB - 1) / WPB;
    float inv_n = 1.0f / (float)n_seg;

    void* args[] = { (void*)&logits, (void*)&cu, (void*)&part, (void*)&out,
                     (void*)&n_seg, (void*)&inv_n };
    hipLaunchCooperativeKernel((void*)rmloss_coop, dim3(blocks),
                               dim3(WPB * 64), args, 0, stream);
}

// Round 3
// 70.044 us; speedup vs baseline: 2.5311x; 2.5311x over previous
//
#include <hip/hip_runtime.h>
#include <math.h>

#define BETA 0.001f
#define WPB  4          // waves per block; one segment per wave

// softplus(x_j - x_i) (i<j) = 0.5*h(x_j-x_i) + 0.5*(x_j-x_i),
//   h(d) = |d| + 2*ln(1+e^{-|d|})
// Sum over pairs:
//   sum_{i<j} softplus = 0.25*(S_full - L*h(0)) + 0.5*sum_k x_k*(2k-L+1)
//   where S_full sums h over ALL ordered (i,j) incl. diagonal, h(0)=2 ln 2.
// l2 term separable: sum_pairs 0.5*(pos^2+neg^2) = 0.5*(L-1)*sum(x^2).
//
// Transcendental reduction: per chain accumulate
//   su = sum |d|,  p = prod (1 + e^{-|d|})   (factors in (1,2], <=127 of
//   them -> p <= 2^127 < FLT_MAX, no overflow)
// then  sum h = su + 2*ln2 * log2(p)  -> ONE v_log_f32 per chain total.
//
// v4 structural change vs v3 (coop, 177 us — grid.sync cost ~100 us) and
// v2 (two dispatches, 70.5 us):
//  * ONE dispatch, NO grid sync, NO atomic-add, NO memset. Each block
//    packs {float partial, MAGIC tag} into one 64-bit AGENT-scope atomic
//    store into d_ws and exits (never waits -> deadlock-free under any
//    block scheduling). Block 0 polls the tags with AGENT-scope acquire
//    loads, sums the 1024 partials, plain-stores out. MAGIC has four
//    distinct bytes so no byte-repeated poison pattern (0xAA..) can
//    alias it. Final reduce rides the main kernel's tail: block 0
//    finishes ~when the last block stores.

typedef unsigned long long u64;
#define MAGIC 0x7F3A9C51u

__device__ __forceinline__ float lane_bcast(float v, int lane_u) {
    // wave-uniform lane index -> v_readlane_b32 (no LDS, no lgkmcnt)
    return __uint_as_float(
        (unsigned)__builtin_amdgcn_readlane((int)__float_as_uint(v), lane_u));
}

__global__ __launch_bounds__(WPB * 64) void rmloss_onepass(
    const float* __restrict__ logits,
    const int*   __restrict__ cu,
    u64*         __restrict__ slot,   // [gridDim.x] packed partials (d_ws)
    float*       __restrict__ out,
    int n_seg, float inv_n)
{
    const int wave = threadIdx.x >> 6;
    const int lane = threadIdx.x & 63;
    const int s = blockIdx.x * WPB + wave;

    __shared__ float wsum[WPB];

    const float kNL2E = -1.44269504088896340736f;  // -log2(e)
    const float kT2L2 =  1.38629436111989061883f;  //  2*ln(2)

    float segval = 0.0f;                // lane0-of-wave contribution

    if (s < n_seg) {                    // wave-uniform guard, NO early return
        const int a   = cu[s];
        const int L   = cu[s + 1] - a;  // 32..127
        const int Lm1 = L - 1;

        const bool a_ok = lane < L;
        const bool b_ok = lane + 64 < L;
        const float va = a_ok ? logits[a + lane] : 0.0f;
        const float vb = b_ok ? logits[a + lane + 64] : 0.0f;

        float su_a = 0.0f, p_a = 1.0f;
        float su_b = 0.0f, p_b = 1.0f;

        if (L > 64) {                       // all va lanes valid here
            #pragma unroll 4
            for (int j = 0; j < 64; ++j) {  // broadcast x[0..63] from va regs
                const float v  = lane_bcast(va, j);
                const float ua = fabsf(va - v);
                su_a += ua;
                p_a = fmaf(p_a, __builtin_amdgcn_exp2f(ua * kNL2E), p_a);
                const float ub = fabsf(vb - v);
                su_b += ub;
                p_b = fmaf(p_b, __builtin_amdgcn_exp2f(ub * kNL2E), p_b);
            }
            const int t2 = L - 64;          // 1..63
            #pragma unroll 4
            for (int j = 0; j < t2; ++j) {  // broadcast x[64..L-1] from vb regs
                const float v  = lane_bcast(vb, j);
                const float ua = fabsf(va - v);
                su_a += ua;
                p_a = fmaf(p_a, __builtin_amdgcn_exp2f(ua * kNL2E), p_a);
                const float ub = fabsf(vb - v);
                su_b += ub;
                p_b = fmaf(p_b, __builtin_amdgcn_exp2f(ub * kNL2E), p_b);
            }
        } else {
            #pragma unroll 4
            for (int j = 0; j < L; ++j) {
                const float v  = lane_bcast(va, j);
                const float ua = fabsf(va - v);
                su_a += ua;
                p_a = fmaf(p_a, __builtin_amdgcn_exp2f(ua * kNL2E), p_a);
            }
        }

        // one log2 per chain (v_log_f32 IS log2 on gfx950)
        const float ha = su_a + kT2L2 * __builtin_amdgcn_logf(p_a);
        const float hb = su_b + kT2L2 * __builtin_amdgcn_logf(p_b);
        const float acch = (a_ok ? ha : 0.0f) + (b_ok ? hb : 0.0f);

        const float lin = va * (float)(2 * lane - Lm1)
                        + vb * (float)(2 * (lane + 64) - Lm1);
        const float sq  = va * va + vb * vb;

        float f = 0.25f * acch + 0.5f * lin + (0.5f * BETA * (float)Lm1) * sq;
        #pragma unroll
        for (int off = 32; off > 0; off >>= 1)
            f += __shfl_down(f, off, 64);

        if (lane == 0) {
            const float P    = 0.5f * (float)(L * Lm1);
            const float diag = 0.25f * (float)L * kT2L2;  // 0.25*L*h(0)
            segval = (f - diag) / P * inv_n;
        }
    }

    if (lane == 0) wsum[wave] = segval;     // inactive waves contribute 0
    __syncthreads();
    if (threadIdx.x == 0) {
        const float p = (wsum[0] + wsum[1]) + (wsum[2] + wsum[3]);
        const u64 packed = ((u64)MAGIC << 32) | (u64)__float_as_uint(p);
        __hip_atomic_store(&slot[blockIdx.x], packed,
                           __ATOMIC_RELEASE, __HIP_MEMORY_SCOPE_AGENT);
    }

    // ---- block 0 finalizes; all other blocks exit (no waiting) ----
    if (blockIdx.x == 0) {
        const int t    = threadIdx.x;
        const int nblk = (int)gridDim.x;
        float acc = 0.0f;

        for (int i = t; i < nblk; i += WPB * 64) {   // 4 slots per thread
            u64 v;
            do {
                v = __hip_atomic_load(&slot[i], __ATOMIC_ACQUIRE,
                                      __HIP_MEMORY_SCOPE_AGENT);
            } while ((unsigned)(v >> 32) != MAGIC);
            acc += __uint_as_float((unsigned)v);
        }

        #pragma unroll
        for (int off = 32; off > 0; off >>= 1)
            acc += __shfl_down(acc, off, 64);

        __syncthreads();                    // wsum reuse is safe after this
        if ((t & 63) == 0) wsum[t >> 6] = acc;
        __syncthreads();
        if (t == 0)
            out[0] = (wsum[0] + wsum[1]) + (wsum[2] + wsum[3]);
    }
}

extern "C" void kernel_launch(void* const* d_in, const int* in_sizes, int n_in,
                              void* d_out, int out_size, void* d_ws, size_t ws_size,
                              hipStream_t stream) {
    (void)n_in; (void)out_size; (void)ws_size;

    const float* logits = (const float*)d_in[0];
    const int*   cu     = (const int*)d_in[1];
    float*       out    = (float*)d_out;
    u64*         slot   = (u64*)d_ws;            // 8*nblocks = 8 KB of ws

    const int n_seg  = in_sizes[1] - 1;
    const int blocks = (n_seg + WPB - 1) / WPB;

    rmloss_onepass<<<blocks, WPB * 64, 0, stream>>>(logits, cu, slot, out,
                                                    n_seg,
                                                    1.0f / (float)n_seg);
}